// Round 13
// baseline (2371.298 us; speedup 1.0000x reference)
//
#include <hip/hip_runtime.h>
#include <cstddef>

#define G_    128
#define NPG_  256
#define EPG_  4096
#define NN_   32768
#define EE_   524288
#define KK_   2048
#define GK_   262144

// d_out layout (floats): [score E][causal_w GK][conf_w GK][causal_ei 2*GK][conf_ei 2*GK][cmask N][dmask N]
#define O_CW  524288
#define O_DW  786432
#define O_CEI 1048576
#define O_FEI 1572864
#define O_CM  2097152
#define O_DM  2129920

typedef float v4f __attribute__((ext_vector_type(4)));
typedef unsigned long long u64;

struct BiasCfg {
  const float* b[8];
};

__device__ __forceinline__ void cswap(u64& a, u64& b, bool d) {
  u64 hi = a > b ? a : b, lo = a > b ? b : a;
  a = d ? hi : lo;
  b = d ? lo : hi;
}

// ---------------- GEMM body, W read from pre-transposed global (L2-resident) ----------------
// nt-envelope preserved: 256-thr block, one contiguous column-panel burst per cb.
// ds_reads halved vs LDS-W version; xT read-only after single barrier (no per-cb barriers).
__device__ __forceinline__ void gemm_wt_body(const float* __restrict__ in, int istride,
                                             const float* __restrict__ WT, int wstride,
                                             const BiasCfg& bc, int ncb,
                                             float* __restrict__ out, int ostride,
                                             int bx, float* xT) {
  const int tid = threadIdx.x;
  const int r0 = bx * 64;
#pragma unroll
  for (int it = 0; it < 16; ++it) {
    int idx = tid + it * 256;
    int rr = idx >> 6, kk = idx & 63;
    xT[kk * 68 + rr] = in[(r0 + rr) * istride + kk];
  }
  __syncthreads();
  const int c4 = (tid & 15) * 4;
  const int r4 = (tid >> 4) * 4;
  for (int cb = 0; cb < ncb; ++cb) {
    const float* wp = WT + cb * 64 + c4;
    const float* bp = bc.b[cb];
    float acc[4][4] = {};
#pragma unroll
    for (int k = 0; k < 64; ++k) {
      float4 xv = *(const float4*)&xT[k * 68 + r4];
      float4 wv = *(const float4*)&wp[(size_t)k * wstride];
      float xr[4] = {xv.x, xv.y, xv.z, xv.w};
      float wc[4] = {wv.x, wv.y, wv.z, wv.w};
#pragma unroll
      for (int a = 0; a < 4; ++a)
#pragma unroll
        for (int b = 0; b < 4; ++b)
          acc[a][b] = fmaf(xr[a], wc[b], acc[a][b]);
    }
    float bx4[4] = {0.f, 0.f, 0.f, 0.f};
    if (bp) {
      float4 bb = *(const float4*)&bp[c4];
      bx4[0] = bb.x; bx4[1] = bb.y; bx4[2] = bb.z; bx4[3] = bb.w;
    }
#pragma unroll
    for (int ri = 0; ri < 4; ++ri) {
      v4f st;
      st.x = acc[ri][0] + bx4[0];
      st.y = acc[ri][1] + bx4[1];
      st.z = acc[ri][2] + bx4[2];
      st.w = acc[ri][3] + bx4[3];
      __builtin_nontemporal_store(st, (v4f*)&out[(r0 + r4 + ri) * ostride + cb * 64 + c4]);
    }
  }
}

__global__ __launch_bounds__(256, 4) void gemm_wt(const float* __restrict__ in, int istride,
                                                  const float* __restrict__ WT, int wstride,
                                                  BiasCfg bc, int ncb,
                                                  float* __restrict__ out, int ostride) {
  __shared__ float xT[64 * 68];
  gemm_wt_body(in, istride, WT, wstride, bc, ncb, out, ostride, blockIdx.x, xT);
}

// ---------------- prep: weight transposes (WmT/W1T/W2T) + zero masks ----------------
// WmT[k*512 + j] = Wm1[(j&255)*128 + ((j<256)?0:64) + k]   (k in [0,64), j in [0,512))
// W1T[k*192 + cb*64+c] = W1{1,2,3}[c*64 + k]; W2T likewise.
__global__ __launch_bounds__(256) void prep_kernel(const float* __restrict__ Wm1,
                                                   const float* __restrict__ W11, const float* __restrict__ W12,
                                                   const float* __restrict__ W13,
                                                   const float* __restrict__ W21, const float* __restrict__ W22,
                                                   const float* __restrict__ W23,
                                                   float* __restrict__ WmT, float* __restrict__ W1T,
                                                   float* __restrict__ W2T, int* __restrict__ masks) {
  const int b = blockIdx.x;
  const int tid = threadIdx.x;
  if (b < 64) {
    const int k = b;
#pragma unroll
    for (int t = 0; t < 2; ++t) {
      int j = t * 256 + tid;
      int row = j & 255;
      int koff = (j < 256) ? 0 : 64;
      WmT[k * 512 + j] = Wm1[row * 128 + koff + k];
    }
  } else if (b < 80) {
    const int kb = (b - 64) * 4;
    if (tid < 192) {
      int cb = tid >> 6, c = tid & 63;
      const float* Wsrc = (cb == 0) ? W11 : (cb == 1) ? W12 : W13;
#pragma unroll
      for (int s = 0; s < 4; ++s) {
        int k = kb + s;
        W1T[k * 192 + tid] = Wsrc[c * 64 + k];
      }
    }
  } else if (b < 96) {
    const int kb = (b - 80) * 4;
    if (tid < 192) {
      int cb = tid >> 6, c = tid & 63;
      const float* Wsrc = (cb == 0) ? W21 : (cb == 1) ? W22 : W23;
#pragma unroll
      for (int s = 0; s < 4; ++s) {
        int k = kb + s;
        W2T[k * 192 + tid] = Wsrc[c * 64 + k];
      }
    }
  } else {
    int idx = (b - 96) * 1024 + tid * 4;  // 64 blocks x 1024 ints = 65536 = 2*NN
    int4 z = {0, 0, 0, 0};
    *(int4*)&masks[idx] = z;
  }
}

// ---------------- phase1: gemm1 (blocks 0..511) + build_M (blocks 512..2559) ----------------
__global__ __launch_bounds__(256, 4) void phase1(const float* __restrict__ x, const float* __restrict__ W1T,
                                                 BiasCfg bc, float* __restrict__ buf,
                                                 const int* __restrict__ ei, const float* __restrict__ ea,
                                                 float* __restrict__ MT, float* __restrict__ Wc) {
  __shared__ float xT[64 * 68];
  if (blockIdx.x >= 512) {
    const int e = (blockIdx.x - 512) * 256 + threadIdx.x;
    const int r = ei[e];
    const int c = ei[EE_ + e];
    const int g = e >> 12;
    const int gb = g << 8;
    const float w = ea[e];
    atomicAdd(&MT[((size_t)g << 16) + ((size_t)(r - gb) << 8) + (c - gb)], w);
    atomicAdd(&Wc[c], w);
    return;
  }
  gemm_wt_body(x, 64, W1T, 192, bc, 3, buf, 192, blockIdx.x, xT);
}

// ---------------- dense leconv aggregation (round-6 proven): h[c] = sum_r MT[r][c]*A[r] - Wc[c]*B[c] + C[c] ----------------
__global__ __launch_bounds__(256) void mm_agg(const float* __restrict__ MT, const float* __restrict__ buf,
                                              const float* __restrict__ Wc, float* __restrict__ hout,
                                              int do_relu) {
  __shared__ float Ms[64 * 72];
  __shared__ float As[64 * 72];
  const int tid = threadIdx.x;
  const int g = blockIdx.x >> 2;
  const int c0 = (blockIdx.x & 3) * 64;
  const int gbase = g * NPG_;
  const size_t mbase = (size_t)g << 16;
  const int c4 = (tid >> 4) * 4;   // output node within tile
  const int k4 = (tid & 15) * 4;   // feature (lane-contiguous)
  float acc[4][4] = {};
  for (int kc = 0; kc < 4; ++kc) {
#pragma unroll
    for (int it = 0; it < 16; ++it) {
      int idx = tid + it * 256;
      int rr = idx >> 6, cc = idx & 63;
      Ms[rr * 72 + cc] = MT[mbase + (size_t)(kc * 64 + rr) * 256 + c0 + cc];
      As[rr * 72 + cc] = buf[(gbase + kc * 64 + rr) * 192 + cc];
    }
    __syncthreads();
#pragma unroll
    for (int r = 0; r < 64; ++r) {
      float4 mv = *(const float4*)&Ms[r * 72 + c4];
      float4 av = *(const float4*)&As[r * 72 + k4];
      float mr[4] = {mv.x, mv.y, mv.z, mv.w};
      float ak[4] = {av.x, av.y, av.z, av.w};
#pragma unroll
      for (int ci = 0; ci < 4; ++ci)
#pragma unroll
        for (int ki = 0; ki < 4; ++ki)
          acc[ci][ki] = fmaf(mr[ci], ak[ki], acc[ci][ki]);
    }
    __syncthreads();
  }
#pragma unroll
  for (int ci = 0; ci < 4; ++ci) {
    int n = gbase + c0 + c4 + ci;
    float wcn = Wc[n];
    float4 b4 = *(const float4*)&buf[n * 192 + 64 + k4];
    float4 cc4 = *(const float4*)&buf[n * 192 + 128 + k4];
    float4 st;
    st.x = acc[ci][0] - wcn * b4.x + cc4.x;
    st.y = acc[ci][1] - wcn * b4.y + cc4.y;
    st.z = acc[ci][2] - wcn * b4.z + cc4.z;
    st.w = acc[ci][3] - wcn * b4.w + cc4.w;
    if (do_relu) {
      st.x = fmaxf(st.x, 0.f); st.y = fmaxf(st.y, 0.f);
      st.z = fmaxf(st.z, 0.f); st.w = fmaxf(st.w, 0.f);
    }
    *(float4*)&hout[n * 64 + k4] = st;
  }
}

// ---------------- fused edge scores v4 (proven): node-major padded LDS, b128 gathers ----------------
__global__ __launch_bounds__(256, 4) void score_v4(const float* __restrict__ pq, const int* __restrict__ ei,
                                                   const float* __restrict__ wm2, const float* __restrict__ bm2,
                                                   float* __restrict__ out) {
  __shared__ float Ps[256 * 20];  // 20 KB
  __shared__ float Qs[256 * 20];  // 20 KB
  const int tid = threadIdx.x;
  const int g = blockIdx.x & 127;
  const int quarter = blockIdx.x >> 7;
  const int gbase = g * NPG_;
  const int ebase = g * EPG_ + quarter * 1024;
  int rl[4], cl[4];
  float acc[4] = {};
#pragma unroll
  for (int j = 0; j < 4; ++j) {
    int e = ebase + j * 256 + tid;
    rl[j] = (ei[e] - gbase) * 20;
    cl[j] = (ei[EE_ + e] - gbase) * 20;
  }
  for (int t = 0; t < 16; ++t) {
    __syncthreads();
#pragma unroll
    for (int it = 0; it < 4; ++it) {
      int idx = tid + it * 256;
      int node = idx >> 2, k4 = (idx & 3) * 4;
      const float* src = &pq[(size_t)(gbase + node) * 512 + t * 16 + k4];
      *(float4*)&Ps[node * 20 + k4] = *(const float4*)src;
      *(float4*)&Qs[node * 20 + k4] = *(const float4*)(src + 256);
    }
    __syncthreads();
#pragma unroll
    for (int k4 = 0; k4 < 16; k4 += 4) {
      float4 w4 = *(const float4*)&wm2[t * 16 + k4];
#pragma unroll
      for (int j = 0; j < 4; ++j) {
        float4 p = *(const float4*)&Ps[rl[j] + k4];
        float4 q = *(const float4*)&Qs[cl[j] + k4];
        acc[j] = fmaf(w4.x, fmaxf(p.x + q.x, 0.f), acc[j]);
        acc[j] = fmaf(w4.y, fmaxf(p.y + q.y, 0.f), acc[j]);
        acc[j] = fmaf(w4.z, fmaxf(p.z + q.z, 0.f), acc[j]);
        acc[j] = fmaf(w4.w, fmaxf(p.w + q.w, 0.f), acc[j]);
      }
    }
  }
  const float beta = bm2[0];
#pragma unroll
  for (int j = 0; j < 4; ++j) out[ebase + j * 256 + tid] = acc[j] + beta;
}

// ---------------- bitonic argsort v4 (proven): registers + shfl_xor; LDS only for j>=256 ----------------
__global__ __launch_bounds__(1024) void sort_kernel(float* __restrict__ out, const int* __restrict__ ei,
                                                    int* __restrict__ kg, int* __restrict__ dg,
                                                    int* __restrict__ cmask, int* __restrict__ dmask) {
  __shared__ u64 keys[EPG_];
  const int g = blockIdx.x;
  const int tid = threadIdx.x;
  const int b = 4 * tid;
  u64 e[4];
  {
    float4 s4 = *(const float4*)&out[g * EPG_ + b];
    float sv[4] = {s4.x, s4.y, s4.z, s4.w};
#pragma unroll
    for (int s = 0; s < 4; ++s) {
      unsigned u = __float_as_uint(sv[s]);
      u = (u & 0x80000000u) ? ~u : (u | 0x80000000u);
      e[s] = ((u64)u << 32) | (unsigned)(~(b + s));
    }
  }
  cswap(e[0], e[1], true);
  cswap(e[2], e[3], false);
  {
    bool d = ((b & 4) == 0);
    cswap(e[0], e[2], d); cswap(e[1], e[3], d);
    cswap(e[0], e[1], d); cswap(e[2], e[3], d);
  }
  for (int k = 8; k <= EPG_; k <<= 1) {
    if (k >= 512) {
#pragma unroll
      for (int s = 0; s < 4; ++s) keys[b + s] = e[s];
      __syncthreads();
      for (int j = k >> 1; j >= 256; j >>= 1) {
        const int jm1 = j - 1;
        const int p0 = tid, p1 = tid + 1024;
        const int i0 = ((p0 & ~jm1) << 1) | (p0 & jm1);
        const int i1 = ((p1 & ~jm1) << 1) | (p1 & jm1);
        u64 a0 = keys[i0], b0 = keys[i0 + j];
        u64 a1 = keys[i1], b1 = keys[i1 + j];
        bool d0 = ((i0 & k) == 0), d1 = ((i1 & k) == 0);
        u64 hi0 = a0 > b0 ? a0 : b0, lo0 = a0 > b0 ? b0 : a0;
        u64 hi1 = a1 > b1 ? a1 : b1, lo1 = a1 > b1 ? b1 : a1;
        keys[i0]     = d0 ? hi0 : lo0;
        keys[i0 + j] = d0 ? lo0 : hi0;
        keys[i1]     = d1 ? hi1 : lo1;
        keys[i1 + j] = d1 ? lo1 : hi1;
        __syncthreads();
      }
#pragma unroll
      for (int s = 0; s < 4; ++s) e[s] = keys[b + s];
    }
    const bool d = ((tid & (k >> 2)) == 0);
    for (int j = (k >> 1) > 128 ? 128 : (k >> 1); j >= 4; j >>= 1) {
      const int delta = j >> 2;
      const bool lower = ((tid & delta) == 0);
      const bool keepmax = (lower == d);
#pragma unroll
      for (int s = 0; s < 4; ++s) {
        u64 p = __shfl_xor(e[s], delta);
        u64 mx = e[s] > p ? e[s] : p;
        u64 mn = e[s] > p ? p : e[s];
        e[s] = keepmax ? mx : mn;
      }
    }
    cswap(e[0], e[2], d); cswap(e[1], e[3], d);
    cswap(e[0], e[1], d); cswap(e[2], e[3], d);
  }
#pragma unroll
  for (int s = 0; s < 4; ++s) {
    const int p = b + s;
    u64 kv = e[s];
    int i = (int)(~(unsigned)kv);
    unsigned hi = (unsigned)(kv >> 32);
    unsigned ub = (hi & 0x80000000u) ? (hi ^ 0x80000000u) : ~hi;
    float sc = __uint_as_float(ub);
    int ed = g * EPG_ + i;
    int r = ei[ed], c = ei[EE_ + ed];
    if (p < KK_) {
      out[O_CW + g * KK_ + p] = sc;
      kg[g * KK_ + p] = ed;
      cmask[r] = 1; cmask[c] = 1;
    } else {
      int q = p - KK_;
      out[O_DW + g * KK_ + q] = -sc;
      dg[g * KK_ + q] = ed;
      dmask[r] = 1; dmask[c] = 1;
    }
  }
}

// ---------------- inclusive scan of masks -> nid (cumsum-1); 1 block per mask ----------------
__global__ __launch_bounds__(1024) void scan_kernel(const int* __restrict__ masks, int* __restrict__ nids) {
  const int which = blockIdx.x;
  const int* m = masks + which * NN_;
  int* nid = nids + which * NN_;
  const int tid = threadIdx.x;
  const int base = tid * 32;
  int local[32];
  int sum = 0;
#pragma unroll
  for (int j = 0; j < 32; ++j) { local[j] = m[base + j]; sum += local[j]; }
  __shared__ int ps[1024];
  ps[tid] = sum;
  __syncthreads();
  for (int off = 1; off < 1024; off <<= 1) {
    int v = (tid >= off) ? ps[tid - off] : 0;
    __syncthreads();
    ps[tid] += v;
    __syncthreads();
  }
  int run = ps[tid] - sum;
#pragma unroll
  for (int j = 0; j < 32; ++j) { run += local[j]; nid[base + j] = run - 1; }
}

// ---------------- final gathers ----------------
__global__ __launch_bounds__(256) void finalize_kernel(const int* __restrict__ kg, const int* __restrict__ dg,
                                                       const int* __restrict__ ei,
                                                       const int* __restrict__ nid_c, const int* __restrict__ nid_d,
                                                       const int* __restrict__ cmask, const int* __restrict__ dmask,
                                                       float* __restrict__ out) {
  const int p = blockIdx.x * 256 + threadIdx.x;
  int e = kg[p];
  out[O_CEI + p]       = (float)nid_c[ei[e]];
  out[O_CEI + GK_ + p] = (float)nid_c[ei[EE_ + e]];
  int e2 = dg[p];
  out[O_FEI + p]       = (float)nid_d[ei[e2]];
  out[O_FEI + GK_ + p] = (float)nid_d[ei[EE_ + e2]];
  if (p < NN_) {
    out[O_CM + p] = (float)cmask[p];
    out[O_DM + p] = (float)dmask[p];
  }
}

extern "C" void kernel_launch(void* const* d_in, const int* in_sizes, int n_in,
                              void* d_out, int out_size, void* d_ws, size_t ws_size,
                              hipStream_t stream) {
  (void)in_sizes; (void)n_in; (void)out_size; (void)ws_size;
  const float* x   = (const float*)d_in[0];
  const float* ea  = (const float*)d_in[1];
  const float* W11 = (const float*)d_in[2];
  const float* b11 = (const float*)d_in[3];
  const float* W12 = (const float*)d_in[4];
  const float* W13 = (const float*)d_in[5];
  const float* b13 = (const float*)d_in[6];
  const float* W21 = (const float*)d_in[7];
  const float* b21 = (const float*)d_in[8];
  const float* W22 = (const float*)d_in[9];
  const float* W23 = (const float*)d_in[10];
  const float* b23 = (const float*)d_in[11];
  const float* Wm1 = (const float*)d_in[12];
  const float* bm1 = (const float*)d_in[13];
  const float* Wm2 = (const float*)d_in[14];
  const float* bm2 = (const float*)d_in[15];
  const int*   ei  = (const int*)d_in[16];
  float* out = (float*)d_out;
  float* ws  = (float*)d_ws;

  // workspace (float offsets), phase-overlapped (unchanged 78.1 MB footprint):
  //   MT  [0, 8388608)          32 MB   (dead after mm_agg #2)
  //   Wc  [8388608, 8421376)    128 KB  adjacent to MT -> single fused memset
  //   buf [8421376, 14712832)   24 MB   (dead after mm_agg #2)
  //   pq  [0, 16777216)         64 MB   overlaps MT/Wc/buf, written after all dead
  //   h_c [16777216, 18874368)  8 MB
  //   ints from 18874368: kg GK, dg GK, cmask N, dmask N, nid_c N, nid_d N
  //   WT aliases kg: WmT 32768 + W1T 12288 + W2T 12288 = 57344 floats < GK.
  //   (WT written by prep, last read by pq gemm; kg written later by sort — no liveness overlap.)
  float* MT  = ws;
  float* Wc  = ws + 8388608;
  float* buf = ws + 8421376;
  float* pq  = ws;
  float* h_c = ws + 16777216;
  int* kg    = (int*)(ws + 18874368);
  int* dg    = kg + GK_;
  int* cmask = dg + GK_;
  int* dmask = cmask + NN_;
  int* nid_c = dmask + NN_;
  int* nid_d = nid_c + NN_;
  float* WmT = ws + 18874368;            // aliases kg
  float* W1T = WmT + 32768;
  float* W2T = W1T + 12288;

  (void)hipMemsetAsync(MT, 0, (size_t)(8388608 + 32768) * sizeof(float), stream);  // MT + Wc

  prep_kernel<<<160, 256, 0, stream>>>(Wm1, W11, W12, W13, W21, W22, W23, WmT, W1T, W2T, cmask);

  BiasCfg bc1{};
  bc1.b[0] = b11; bc1.b[1] = nullptr; bc1.b[2] = b13;
  phase1<<<2560, 256, 0, stream>>>(x, W1T, bc1, buf, ei, ea, MT, Wc);

  mm_agg<<<512, 256, 0, stream>>>(MT, buf, Wc, h_c, /*relu=*/1);

  BiasCfg bc2{};
  bc2.b[0] = b21; bc2.b[1] = nullptr; bc2.b[2] = b23;
  gemm_wt<<<512, 256, 0, stream>>>(h_c, 64, W2T, 192, bc2, 3, buf, 192);

  mm_agg<<<512, 256, 0, stream>>>(MT, buf, Wc, h_c, /*relu=*/0);

  BiasCfg bc3{};
  for (int cb = 0; cb < 4; ++cb) { bc3.b[cb] = bm1 + cb * 64; bc3.b[cb + 4] = nullptr; }
  gemm_wt<<<512, 256, 0, stream>>>(h_c, 64, WmT, 512, bc3, 8, pq, 512);

  score_v4<<<512, 256, 0, stream>>>(pq, ei, Wm2, bm2, out);

  sort_kernel<<<G_, 1024, 0, stream>>>(out, ei, kg, dg, cmask, dmask);

  scan_kernel<<<2, 1024, 0, stream>>>(cmask, nid_c);

  finalize_kernel<<<GK_ / 256, 256, 0, stream>>>(kg, dg, ei, nid_c, nid_d, cmask, dmask, out);
}

// Round 14
// 360.049 us; speedup vs baseline: 6.5860x; 6.5860x over previous
//
#include <hip/hip_runtime.h>
#include <cstddef>

#define G_    128
#define NPG_  256
#define EPG_  4096
#define NN_   32768
#define EE_   524288
#define KK_   2048
#define GK_   262144

// d_out layout (floats): [score E][causal_w GK][conf_w GK][causal_ei 2*GK][conf_ei 2*GK][cmask N][dmask N]
#define O_CW  524288
#define O_DW  786432
#define O_CEI 1048576
#define O_FEI 1572864
#define O_CM  2097152
#define O_DM  2129920

typedef float v4f __attribute__((ext_vector_type(4)));
typedef unsigned long long u64;

struct BiasCfg {
  const float* b[8];
};

__device__ __forceinline__ void cswap(u64& a, u64& b, bool d) {
  u64 hi = a > b ? a : b, lo = a > b ? b : a;
  a = d ? hi : lo;
  b = d ? lo : hi;
}

// ---------------- GEMM body, W from pre-transposed global; nt-envelope rule (r6/7/8/9/13):
// <=1 outstanding nt panel stream per block — enforce with __syncthreads() AFTER each cb's
// store burst. Removing that barrier (r13) caused ~20x HBM write amplification. ----------------
__device__ __forceinline__ void gemm_wt_body(const float* __restrict__ in, int istride,
                                             const float* __restrict__ WT, int wstride,
                                             const BiasCfg& bc, int ncb,
                                             float* __restrict__ out, int ostride,
                                             int bx, float* xT) {
  const int tid = threadIdx.x;
  const int r0 = bx * 64;
#pragma unroll
  for (int it = 0; it < 16; ++it) {
    int idx = tid + it * 256;
    int rr = idx >> 6, kk = idx & 63;
    xT[kk * 68 + rr] = in[(r0 + rr) * istride + kk];
  }
  __syncthreads();
  const int c4 = (tid & 15) * 4;
  const int r4 = (tid >> 4) * 4;
  for (int cb = 0; cb < ncb; ++cb) {
    const float* wp = WT + cb * 64 + c4;
    const float* bp = bc.b[cb];
    float acc[4][4] = {};
#pragma unroll
    for (int k = 0; k < 64; ++k) {
      float4 xv = *(const float4*)&xT[k * 68 + r4];
      float4 wv = *(const float4*)&wp[(size_t)k * wstride];
      float xr[4] = {xv.x, xv.y, xv.z, xv.w};
      float wc[4] = {wv.x, wv.y, wv.z, wv.w};
#pragma unroll
      for (int a = 0; a < 4; ++a)
#pragma unroll
        for (int b = 0; b < 4; ++b)
          acc[a][b] = fmaf(xr[a], wc[b], acc[a][b]);
    }
    float bx4[4] = {0.f, 0.f, 0.f, 0.f};
    if (bp) {
      float4 bb = *(const float4*)&bp[c4];
      bx4[0] = bb.x; bx4[1] = bb.y; bx4[2] = bb.z; bx4[3] = bb.w;
    }
#pragma unroll
    for (int ri = 0; ri < 4; ++ri) {
      v4f st;
      st.x = acc[ri][0] + bx4[0];
      st.y = acc[ri][1] + bx4[1];
      st.z = acc[ri][2] + bx4[2];
      st.w = acc[ri][3] + bx4[3];
      __builtin_nontemporal_store(st, (v4f*)&out[(r0 + r4 + ri) * ostride + cb * 64 + c4]);
    }
    __syncthreads();  // drain nt burst (vmcnt(0)) — the nt-envelope invariant
  }
}

__global__ __launch_bounds__(256, 4) void gemm_wt(const float* __restrict__ in, int istride,
                                                  const float* __restrict__ WT, int wstride,
                                                  BiasCfg bc, int ncb,
                                                  float* __restrict__ out, int ostride) {
  __shared__ float xT[64 * 68];
  gemm_wt_body(in, istride, WT, wstride, bc, ncb, out, ostride, blockIdx.x, xT);
}

// ---------------- prep: weight transposes (WmT/W1T/W2T) + zero masks ----------------
__global__ __launch_bounds__(256) void prep_kernel(const float* __restrict__ Wm1,
                                                   const float* __restrict__ W11, const float* __restrict__ W12,
                                                   const float* __restrict__ W13,
                                                   const float* __restrict__ W21, const float* __restrict__ W22,
                                                   const float* __restrict__ W23,
                                                   float* __restrict__ WmT, float* __restrict__ W1T,
                                                   float* __restrict__ W2T, int* __restrict__ masks) {
  const int b = blockIdx.x;
  const int tid = threadIdx.x;
  if (b < 64) {
    const int k = b;
#pragma unroll
    for (int t = 0; t < 2; ++t) {
      int j = t * 256 + tid;
      int row = j & 255;
      int koff = (j < 256) ? 0 : 64;
      WmT[k * 512 + j] = Wm1[row * 128 + koff + k];
    }
  } else if (b < 80) {
    const int kb = (b - 64) * 4;
    if (tid < 192) {
      int cb = tid >> 6, c = tid & 63;
      const float* Wsrc = (cb == 0) ? W11 : (cb == 1) ? W12 : W13;
#pragma unroll
      for (int s = 0; s < 4; ++s) {
        int k = kb + s;
        W1T[k * 192 + tid] = Wsrc[c * 64 + k];
      }
    }
  } else if (b < 96) {
    const int kb = (b - 80) * 4;
    if (tid < 192) {
      int cb = tid >> 6, c = tid & 63;
      const float* Wsrc = (cb == 0) ? W21 : (cb == 1) ? W22 : W23;
#pragma unroll
      for (int s = 0; s < 4; ++s) {
        int k = kb + s;
        W2T[k * 192 + tid] = Wsrc[c * 64 + k];
      }
    }
  } else {
    int idx = (b - 96) * 1024 + tid * 4;  // 64 blocks x 1024 ints = 65536 = 2*NN
    int4 z = {0, 0, 0, 0};
    *(int4*)&masks[idx] = z;
  }
}

// ---------------- phase1: gemm1 (blocks 0..511) + build_M (blocks 512..2559) ----------------
__global__ __launch_bounds__(256, 4) void phase1(const float* __restrict__ x, const float* __restrict__ W1T,
                                                 BiasCfg bc, float* __restrict__ buf,
                                                 const int* __restrict__ ei, const float* __restrict__ ea,
                                                 float* __restrict__ MT, float* __restrict__ Wc) {
  __shared__ float xT[64 * 68];
  if (blockIdx.x >= 512) {
    const int e = (blockIdx.x - 512) * 256 + threadIdx.x;
    const int r = ei[e];
    const int c = ei[EE_ + e];
    const int g = e >> 12;
    const int gb = g << 8;
    const float w = ea[e];
    atomicAdd(&MT[((size_t)g << 16) + ((size_t)(r - gb) << 8) + (c - gb)], w);
    atomicAdd(&Wc[c], w);
    return;
  }
  gemm_wt_body(x, 64, W1T, 192, bc, 3, buf, 192, blockIdx.x, xT);
}

// ---------------- dense leconv aggregation (round-6 proven): h[c] = sum_r MT[r][c]*A[r] - Wc[c]*B[c] + C[c] ----------------
__global__ __launch_bounds__(256) void mm_agg(const float* __restrict__ MT, const float* __restrict__ buf,
                                              const float* __restrict__ Wc, float* __restrict__ hout,
                                              int do_relu) {
  __shared__ float Ms[64 * 72];
  __shared__ float As[64 * 72];
  const int tid = threadIdx.x;
  const int g = blockIdx.x >> 2;
  const int c0 = (blockIdx.x & 3) * 64;
  const int gbase = g * NPG_;
  const size_t mbase = (size_t)g << 16;
  const int c4 = (tid >> 4) * 4;   // output node within tile
  const int k4 = (tid & 15) * 4;   // feature (lane-contiguous)
  float acc[4][4] = {};
  for (int kc = 0; kc < 4; ++kc) {
#pragma unroll
    for (int it = 0; it < 16; ++it) {
      int idx = tid + it * 256;
      int rr = idx >> 6, cc = idx & 63;
      Ms[rr * 72 + cc] = MT[mbase + (size_t)(kc * 64 + rr) * 256 + c0 + cc];
      As[rr * 72 + cc] = buf[(gbase + kc * 64 + rr) * 192 + cc];
    }
    __syncthreads();
#pragma unroll
    for (int r = 0; r < 64; ++r) {
      float4 mv = *(const float4*)&Ms[r * 72 + c4];
      float4 av = *(const float4*)&As[r * 72 + k4];
      float mr[4] = {mv.x, mv.y, mv.z, mv.w};
      float ak[4] = {av.x, av.y, av.z, av.w};
#pragma unroll
      for (int ci = 0; ci < 4; ++ci)
#pragma unroll
        for (int ki = 0; ki < 4; ++ki)
          acc[ci][ki] = fmaf(mr[ci], ak[ki], acc[ci][ki]);
    }
    __syncthreads();
  }
#pragma unroll
  for (int ci = 0; ci < 4; ++ci) {
    int n = gbase + c0 + c4 + ci;
    float wcn = Wc[n];
    float4 b4 = *(const float4*)&buf[n * 192 + 64 + k4];
    float4 cc4 = *(const float4*)&buf[n * 192 + 128 + k4];
    float4 st;
    st.x = acc[ci][0] - wcn * b4.x + cc4.x;
    st.y = acc[ci][1] - wcn * b4.y + cc4.y;
    st.z = acc[ci][2] - wcn * b4.z + cc4.z;
    st.w = acc[ci][3] - wcn * b4.w + cc4.w;
    if (do_relu) {
      st.x = fmaxf(st.x, 0.f); st.y = fmaxf(st.y, 0.f);
      st.z = fmaxf(st.z, 0.f); st.w = fmaxf(st.w, 0.f);
    }
    *(float4*)&hout[n * 64 + k4] = st;
  }
}

// ---------------- fused edge scores v4 (proven): node-major padded LDS, b128 gathers ----------------
__global__ __launch_bounds__(256, 4) void score_v4(const float* __restrict__ pq, const int* __restrict__ ei,
                                                   const float* __restrict__ wm2, const float* __restrict__ bm2,
                                                   float* __restrict__ out) {
  __shared__ float Ps[256 * 20];  // 20 KB
  __shared__ float Qs[256 * 20];  // 20 KB
  const int tid = threadIdx.x;
  const int g = blockIdx.x & 127;
  const int quarter = blockIdx.x >> 7;
  const int gbase = g * NPG_;
  const int ebase = g * EPG_ + quarter * 1024;
  int rl[4], cl[4];
  float acc[4] = {};
#pragma unroll
  for (int j = 0; j < 4; ++j) {
    int e = ebase + j * 256 + tid;
    rl[j] = (ei[e] - gbase) * 20;
    cl[j] = (ei[EE_ + e] - gbase) * 20;
  }
  for (int t = 0; t < 16; ++t) {
    __syncthreads();
#pragma unroll
    for (int it = 0; it < 4; ++it) {
      int idx = tid + it * 256;
      int node = idx >> 2, k4 = (idx & 3) * 4;
      const float* src = &pq[(size_t)(gbase + node) * 512 + t * 16 + k4];
      *(float4*)&Ps[node * 20 + k4] = *(const float4*)src;
      *(float4*)&Qs[node * 20 + k4] = *(const float4*)(src + 256);
    }
    __syncthreads();
#pragma unroll
    for (int k4 = 0; k4 < 16; k4 += 4) {
      float4 w4 = *(const float4*)&wm2[t * 16 + k4];
#pragma unroll
      for (int j = 0; j < 4; ++j) {
        float4 p = *(const float4*)&Ps[rl[j] + k4];
        float4 q = *(const float4*)&Qs[cl[j] + k4];
        acc[j] = fmaf(w4.x, fmaxf(p.x + q.x, 0.f), acc[j]);
        acc[j] = fmaf(w4.y, fmaxf(p.y + q.y, 0.f), acc[j]);
        acc[j] = fmaf(w4.z, fmaxf(p.z + q.z, 0.f), acc[j]);
        acc[j] = fmaf(w4.w, fmaxf(p.w + q.w, 0.f), acc[j]);
      }
    }
  }
  const float beta = bm2[0];
#pragma unroll
  for (int j = 0; j < 4; ++j) out[ebase + j * 256 + tid] = acc[j] + beta;
}

// ---------------- bitonic argsort v4 (proven): registers + shfl_xor; LDS only for j>=256 ----------------
__global__ __launch_bounds__(1024) void sort_kernel(float* __restrict__ out, const int* __restrict__ ei,
                                                    int* __restrict__ kg, int* __restrict__ dg,
                                                    int* __restrict__ cmask, int* __restrict__ dmask) {
  __shared__ u64 keys[EPG_];
  const int g = blockIdx.x;
  const int tid = threadIdx.x;
  const int b = 4 * tid;
  u64 e[4];
  {
    float4 s4 = *(const float4*)&out[g * EPG_ + b];
    float sv[4] = {s4.x, s4.y, s4.z, s4.w};
#pragma unroll
    for (int s = 0; s < 4; ++s) {
      unsigned u = __float_as_uint(sv[s]);
      u = (u & 0x80000000u) ? ~u : (u | 0x80000000u);
      e[s] = ((u64)u << 32) | (unsigned)(~(b + s));
    }
  }
  cswap(e[0], e[1], true);
  cswap(e[2], e[3], false);
  {
    bool d = ((b & 4) == 0);
    cswap(e[0], e[2], d); cswap(e[1], e[3], d);
    cswap(e[0], e[1], d); cswap(e[2], e[3], d);
  }
  for (int k = 8; k <= EPG_; k <<= 1) {
    if (k >= 512) {
#pragma unroll
      for (int s = 0; s < 4; ++s) keys[b + s] = e[s];
      __syncthreads();
      for (int j = k >> 1; j >= 256; j >>= 1) {
        const int jm1 = j - 1;
        const int p0 = tid, p1 = tid + 1024;
        const int i0 = ((p0 & ~jm1) << 1) | (p0 & jm1);
        const int i1 = ((p1 & ~jm1) << 1) | (p1 & jm1);
        u64 a0 = keys[i0], b0 = keys[i0 + j];
        u64 a1 = keys[i1], b1 = keys[i1 + j];
        bool d0 = ((i0 & k) == 0), d1 = ((i1 & k) == 0);
        u64 hi0 = a0 > b0 ? a0 : b0, lo0 = a0 > b0 ? b0 : a0;
        u64 hi1 = a1 > b1 ? a1 : b1, lo1 = a1 > b1 ? b1 : a1;
        keys[i0]     = d0 ? hi0 : lo0;
        keys[i0 + j] = d0 ? lo0 : hi0;
        keys[i1]     = d1 ? hi1 : lo1;
        keys[i1 + j] = d1 ? lo1 : hi1;
        __syncthreads();
      }
#pragma unroll
      for (int s = 0; s < 4; ++s) e[s] = keys[b + s];
    }
    const bool d = ((tid & (k >> 2)) == 0);
    for (int j = (k >> 1) > 128 ? 128 : (k >> 1); j >= 4; j >>= 1) {
      const int delta = j >> 2;
      const bool lower = ((tid & delta) == 0);
      const bool keepmax = (lower == d);
#pragma unroll
      for (int s = 0; s < 4; ++s) {
        u64 p = __shfl_xor(e[s], delta);
        u64 mx = e[s] > p ? e[s] : p;
        u64 mn = e[s] > p ? p : e[s];
        e[s] = keepmax ? mx : mn;
      }
    }
    cswap(e[0], e[2], d); cswap(e[1], e[3], d);
    cswap(e[0], e[1], d); cswap(e[2], e[3], d);
  }
#pragma unroll
  for (int s = 0; s < 4; ++s) {
    const int p = b + s;
    u64 kv = e[s];
    int i = (int)(~(unsigned)kv);
    unsigned hi = (unsigned)(kv >> 32);
    unsigned ub = (hi & 0x80000000u) ? (hi ^ 0x80000000u) : ~hi;
    float sc = __uint_as_float(ub);
    int ed = g * EPG_ + i;
    int r = ei[ed], c = ei[EE_ + ed];
    if (p < KK_) {
      out[O_CW + g * KK_ + p] = sc;
      kg[g * KK_ + p] = ed;
      cmask[r] = 1; cmask[c] = 1;
    } else {
      int q = p - KK_;
      out[O_DW + g * KK_ + q] = -sc;
      dg[g * KK_ + q] = ed;
      dmask[r] = 1; dmask[c] = 1;
    }
  }
}

// ---------------- inclusive scan of masks -> nid (cumsum-1); 1 block per mask ----------------
__global__ __launch_bounds__(1024) void scan_kernel(const int* __restrict__ masks, int* __restrict__ nids) {
  const int which = blockIdx.x;
  const int* m = masks + which * NN_;
  int* nid = nids + which * NN_;
  const int tid = threadIdx.x;
  const int base = tid * 32;
  int local[32];
  int sum = 0;
#pragma unroll
  for (int j = 0; j < 32; ++j) { local[j] = m[base + j]; sum += local[j]; }
  __shared__ int ps[1024];
  ps[tid] = sum;
  __syncthreads();
  for (int off = 1; off < 1024; off <<= 1) {
    int v = (tid >= off) ? ps[tid - off] : 0;
    __syncthreads();
    ps[tid] += v;
    __syncthreads();
  }
  int run = ps[tid] - sum;
#pragma unroll
  for (int j = 0; j < 32; ++j) { run += local[j]; nid[base + j] = run - 1; }
}

// ---------------- final gathers ----------------
__global__ __launch_bounds__(256) void finalize_kernel(const int* __restrict__ kg, const int* __restrict__ dg,
                                                       const int* __restrict__ ei,
                                                       const int* __restrict__ nid_c, const int* __restrict__ nid_d,
                                                       const int* __restrict__ cmask, const int* __restrict__ dmask,
                                                       float* __restrict__ out) {
  const int p = blockIdx.x * 256 + threadIdx.x;
  int e = kg[p];
  out[O_CEI + p]       = (float)nid_c[ei[e]];
  out[O_CEI + GK_ + p] = (float)nid_c[ei[EE_ + e]];
  int e2 = dg[p];
  out[O_FEI + p]       = (float)nid_d[ei[e2]];
  out[O_FEI + GK_ + p] = (float)nid_d[ei[EE_ + e2]];
  if (p < NN_) {
    out[O_CM + p] = (float)cmask[p];
    out[O_DM + p] = (float)dmask[p];
  }
}

extern "C" void kernel_launch(void* const* d_in, const int* in_sizes, int n_in,
                              void* d_out, int out_size, void* d_ws, size_t ws_size,
                              hipStream_t stream) {
  (void)in_sizes; (void)n_in; (void)out_size; (void)ws_size;
  const float* x   = (const float*)d_in[0];
  const float* ea  = (const float*)d_in[1];
  const float* W11 = (const float*)d_in[2];
  const float* b11 = (const float*)d_in[3];
  const float* W12 = (const float*)d_in[4];
  const float* W13 = (const float*)d_in[5];
  const float* b13 = (const float*)d_in[6];
  const float* W21 = (const float*)d_in[7];
  const float* b21 = (const float*)d_in[8];
  const float* W22 = (const float*)d_in[9];
  const float* W23 = (const float*)d_in[10];
  const float* b23 = (const float*)d_in[11];
  const float* Wm1 = (const float*)d_in[12];
  const float* bm1 = (const float*)d_in[13];
  const float* Wm2 = (const float*)d_in[14];
  const float* bm2 = (const float*)d_in[15];
  const int*   ei  = (const int*)d_in[16];
  float* out = (float*)d_out;
  float* ws  = (float*)d_ws;

  // workspace (float offsets), phase-overlapped (unchanged 78.1 MB footprint):
  //   MT  [0, 8388608)          32 MB   (dead after mm_agg #2)
  //   Wc  [8388608, 8421376)    128 KB  adjacent to MT -> single fused memset
  //   buf [8421376, 14712832)   24 MB   (dead after mm_agg #2)
  //   pq  [0, 16777216)         64 MB   overlaps MT/Wc/buf, written after all dead
  //   h_c [16777216, 18874368)  8 MB
  //   ints from 18874368: kg GK, dg GK, cmask N, dmask N, nid_c N, nid_d N
  //   WT aliases kg: WmT 32768 + W1T 12288 + W2T 12288 = 57344 floats < GK.
  float* MT  = ws;
  float* Wc  = ws + 8388608;
  float* buf = ws + 8421376;
  float* pq  = ws;
  float* h_c = ws + 16777216;
  int* kg    = (int*)(ws + 18874368);
  int* dg    = kg + GK_;
  int* cmask = dg + GK_;
  int* dmask = cmask + NN_;
  int* nid_c = dmask + NN_;
  int* nid_d = nid_c + NN_;
  float* WmT = ws + 18874368;            // aliases kg
  float* W1T = WmT + 32768;
  float* W2T = W1T + 12288;

  (void)hipMemsetAsync(MT, 0, (size_t)(8388608 + 32768) * sizeof(float), stream);  // MT + Wc

  prep_kernel<<<160, 256, 0, stream>>>(Wm1, W11, W12, W13, W21, W22, W23, WmT, W1T, W2T, cmask);

  BiasCfg bc1{};
  bc1.b[0] = b11; bc1.b[1] = nullptr; bc1.b[2] = b13;
  phase1<<<2560, 256, 0, stream>>>(x, W1T, bc1, buf, ei, ea, MT, Wc);

  mm_agg<<<512, 256, 0, stream>>>(MT, buf, Wc, h_c, /*relu=*/1);

  BiasCfg bc2{};
  bc2.b[0] = b21; bc2.b[1] = nullptr; bc2.b[2] = b23;
  gemm_wt<<<512, 256, 0, stream>>>(h_c, 64, W2T, 192, bc2, 3, buf, 192);

  mm_agg<<<512, 256, 0, stream>>>(MT, buf, Wc, h_c, /*relu=*/0);

  BiasCfg bc3{};
  for (int cb = 0; cb < 4; ++cb) { bc3.b[cb] = bm1 + cb * 64; bc3.b[cb + 4] = nullptr; }
  gemm_wt<<<512, 256, 0, stream>>>(h_c, 64, WmT, 512, bc3, 8, pq, 512);

  score_v4<<<512, 256, 0, stream>>>(pq, ei, Wm2, bm2, out);

  sort_kernel<<<G_, 1024, 0, stream>>>(out, ei, kg, dg, cmask, dmask);

  scan_kernel<<<2, 1024, 0, stream>>>(cmask, nid_c);

  finalize_kernel<<<GK_ / 256, 256, 0, stream>>>(kg, dg, ei, nid_c, nid_d, cmask, dmask, out);
}

// Round 15
// 329.093 us; speedup vs baseline: 7.2056x; 1.0941x over previous
//
#include <hip/hip_runtime.h>
#include <cstddef>

#define G_    128
#define NPG_  256
#define EPG_  4096
#define NN_   32768
#define EE_   524288
#define KK_   2048
#define GK_   262144

// d_out layout (floats): [score E][causal_w GK][conf_w GK][causal_ei 2*GK][conf_ei 2*GK][cmask N][dmask N]
#define O_CW  524288
#define O_DW  786432
#define O_CEI 1048576
#define O_FEI 1572864
#define O_CM  2097152
#define O_DM  2129920

typedef float v4f __attribute__((ext_vector_type(4)));
typedef unsigned long long u64;

struct BiasCfg {
  const float* b[8];
};

__device__ __forceinline__ void cswap(u64& a, u64& b, bool d) {
  u64 hi = a > b ? a : b, lo = a > b ? b : a;
  a = d ? hi : lo;
  b = d ? lo : hi;
}

// ---------------- GEMM body, W from pre-transposed global; nt-envelope rule (r6/7/8/9/13):
// <=1 outstanding nt panel stream per block — enforce with __syncthreads() AFTER each cb's
// store burst. Removing that barrier (r13) caused ~20x HBM write amplification. ----------------
__device__ __forceinline__ void gemm_wt_body(const float* __restrict__ in, int istride,
                                             const float* __restrict__ WT, int wstride,
                                             const BiasCfg& bc, int ncb,
                                             float* __restrict__ out, int ostride,
                                             int bx, float* xT) {
  const int tid = threadIdx.x;
  const int r0 = bx * 64;
#pragma unroll
  for (int it = 0; it < 16; ++it) {
    int idx = tid + it * 256;
    int rr = idx >> 6, kk = idx & 63;
    xT[kk * 68 + rr] = in[(r0 + rr) * istride + kk];
  }
  __syncthreads();
  const int c4 = (tid & 15) * 4;
  const int r4 = (tid >> 4) * 4;
  for (int cb = 0; cb < ncb; ++cb) {
    const float* wp = WT + cb * 64 + c4;
    const float* bp = bc.b[cb];
    float acc[4][4] = {};
#pragma unroll
    for (int k = 0; k < 64; ++k) {
      float4 xv = *(const float4*)&xT[k * 68 + r4];
      float4 wv = *(const float4*)&wp[(size_t)k * wstride];
      float xr[4] = {xv.x, xv.y, xv.z, xv.w};
      float wc[4] = {wv.x, wv.y, wv.z, wv.w};
#pragma unroll
      for (int a = 0; a < 4; ++a)
#pragma unroll
        for (int b = 0; b < 4; ++b)
          acc[a][b] = fmaf(xr[a], wc[b], acc[a][b]);
    }
    float bx4[4] = {0.f, 0.f, 0.f, 0.f};
    if (bp) {
      float4 bb = *(const float4*)&bp[c4];
      bx4[0] = bb.x; bx4[1] = bb.y; bx4[2] = bb.z; bx4[3] = bb.w;
    }
#pragma unroll
    for (int ri = 0; ri < 4; ++ri) {
      v4f st;
      st.x = acc[ri][0] + bx4[0];
      st.y = acc[ri][1] + bx4[1];
      st.z = acc[ri][2] + bx4[2];
      st.w = acc[ri][3] + bx4[3];
      __builtin_nontemporal_store(st, (v4f*)&out[(r0 + r4 + ri) * ostride + cb * 64 + c4]);
    }
    __syncthreads();  // drain nt burst (vmcnt(0)) — the nt-envelope invariant
  }
}

__global__ __launch_bounds__(256, 4) void gemm_wt(const float* __restrict__ in, int istride,
                                                  const float* __restrict__ WT, int wstride,
                                                  BiasCfg bc, int ncb,
                                                  float* __restrict__ out, int ostride) {
  __shared__ float xT[64 * 68];
  gemm_wt_body(in, istride, WT, wstride, bc, ncb, out, ostride, blockIdx.x, xT);
}

// ---------------- prep: weight transposes (WmT/W1T/W2T) + zero masks ----------------
__global__ __launch_bounds__(256) void prep_kernel(const float* __restrict__ Wm1,
                                                   const float* __restrict__ W11, const float* __restrict__ W12,
                                                   const float* __restrict__ W13,
                                                   const float* __restrict__ W21, const float* __restrict__ W22,
                                                   const float* __restrict__ W23,
                                                   float* __restrict__ WmT, float* __restrict__ W1T,
                                                   float* __restrict__ W2T, int* __restrict__ masks) {
  const int b = blockIdx.x;
  const int tid = threadIdx.x;
  if (b < 64) {
    const int k = b;
#pragma unroll
    for (int t = 0; t < 2; ++t) {
      int j = t * 256 + tid;
      int row = j & 255;
      int koff = (j < 256) ? 0 : 64;
      WmT[k * 512 + j] = Wm1[row * 128 + koff + k];
    }
  } else if (b < 80) {
    const int kb = (b - 64) * 4;
    if (tid < 192) {
      int cb = tid >> 6, c = tid & 63;
      const float* Wsrc = (cb == 0) ? W11 : (cb == 1) ? W12 : W13;
#pragma unroll
      for (int s = 0; s < 4; ++s) {
        int k = kb + s;
        W1T[k * 192 + tid] = Wsrc[c * 64 + k];
      }
    }
  } else if (b < 96) {
    const int kb = (b - 80) * 4;
    if (tid < 192) {
      int cb = tid >> 6, c = tid & 63;
      const float* Wsrc = (cb == 0) ? W21 : (cb == 1) ? W22 : W23;
#pragma unroll
      for (int s = 0; s < 4; ++s) {
        int k = kb + s;
        W2T[k * 192 + tid] = Wsrc[c * 64 + k];
      }
    }
  } else {
    int idx = (b - 96) * 1024 + tid * 4;  // 64 blocks x 1024 ints = 65536 = 2*NN
    int4 z = {0, 0, 0, 0};
    *(int4*)&masks[idx] = z;
  }
}

// ---------------- build_dense: per-(group, col-half) LDS accumulation — no global atomics,
// no MT memset (every cell written), Wc = LDS column sums (no contention) ----------------
__global__ __launch_bounds__(256) void build_dense(const int* __restrict__ ei, const float* __restrict__ ea,
                                                   float* __restrict__ MT, float* __restrict__ Wc) {
  __shared__ float acc[NPG_ * 128];  // 128 KB: 256 rows x 128 cols (this block's column half)
  const int tid = threadIdx.x;
  const int g = blockIdx.x >> 1;
  const int c0 = (blockIdx.x & 1) * 128;
  const int gbase = g * NPG_;
  const size_t mbase = (size_t)g << 16;
  for (int i = tid * 4; i < NPG_ * 128; i += 1024) {
    float4 z = {0.f, 0.f, 0.f, 0.f};
    *(float4*)&acc[i] = z;
  }
  __syncthreads();
  const int ebase = g * EPG_;
#pragma unroll
  for (int it = 0; it < 16; ++it) {
    int e = ebase + it * 256 + tid;
    int r = ei[e] - gbase;
    int ch = ei[EE_ + e] - gbase - c0;
    float w = ea[e];
    if ((unsigned)ch < 128u) atomicAdd(&acc[r * 128 + ch], w);
  }
  __syncthreads();
  // write the half-slab: each row contributes 512 B aligned chunk
  for (int i = tid; i < NPG_ * 32; i += 256) {
    int r = i >> 5, c4 = (i & 31) * 4;
    *(float4*)&MT[mbase + (size_t)r * 256 + c0 + c4] = *(const float4*)&acc[r * 128 + c4];
  }
  // Wc column sums (lanes own columns; per-lane serial over r)
  if (tid < 128) {
    float s = 0.f;
    for (int r = 0; r < NPG_; ++r) s += acc[r * 128 + tid];
    Wc[gbase + c0 + tid] = s;
  }
}

// ---------------- dense leconv aggregation (round-6 proven): h[c] = sum_r MT[r][c]*A[r] - Wc[c]*B[c] + C[c] ----------------
__global__ __launch_bounds__(256) void mm_agg(const float* __restrict__ MT, const float* __restrict__ buf,
                                              const float* __restrict__ Wc, float* __restrict__ hout,
                                              int do_relu) {
  __shared__ float Ms[64 * 72];
  __shared__ float As[64 * 72];
  const int tid = threadIdx.x;
  const int g = blockIdx.x >> 2;
  const int c0 = (blockIdx.x & 3) * 64;
  const int gbase = g * NPG_;
  const size_t mbase = (size_t)g << 16;
  const int c4 = (tid >> 4) * 4;   // output node within tile
  const int k4 = (tid & 15) * 4;   // feature (lane-contiguous)
  float acc[4][4] = {};
  for (int kc = 0; kc < 4; ++kc) {
#pragma unroll
    for (int it = 0; it < 16; ++it) {
      int idx = tid + it * 256;
      int rr = idx >> 6, cc = idx & 63;
      Ms[rr * 72 + cc] = MT[mbase + (size_t)(kc * 64 + rr) * 256 + c0 + cc];
      As[rr * 72 + cc] = buf[(gbase + kc * 64 + rr) * 192 + cc];
    }
    __syncthreads();
#pragma unroll
    for (int r = 0; r < 64; ++r) {
      float4 mv = *(const float4*)&Ms[r * 72 + c4];
      float4 av = *(const float4*)&As[r * 72 + k4];
      float mr[4] = {mv.x, mv.y, mv.z, mv.w};
      float ak[4] = {av.x, av.y, av.z, av.w};
#pragma unroll
      for (int ci = 0; ci < 4; ++ci)
#pragma unroll
        for (int ki = 0; ki < 4; ++ki)
          acc[ci][ki] = fmaf(mr[ci], ak[ki], acc[ci][ki]);
    }
    __syncthreads();
  }
#pragma unroll
  for (int ci = 0; ci < 4; ++ci) {
    int n = gbase + c0 + c4 + ci;
    float wcn = Wc[n];
    float4 b4 = *(const float4*)&buf[n * 192 + 64 + k4];
    float4 cc4 = *(const float4*)&buf[n * 192 + 128 + k4];
    float4 st;
    st.x = acc[ci][0] - wcn * b4.x + cc4.x;
    st.y = acc[ci][1] - wcn * b4.y + cc4.y;
    st.z = acc[ci][2] - wcn * b4.z + cc4.z;
    st.w = acc[ci][3] - wcn * b4.w + cc4.w;
    if (do_relu) {
      st.x = fmaxf(st.x, 0.f); st.y = fmaxf(st.y, 0.f);
      st.z = fmaxf(st.z, 0.f); st.w = fmaxf(st.w, 0.f);
    }
    *(float4*)&hout[n * 64 + k4] = st;
  }
}

// ---------------- fused edge scores v4 (proven): node-major padded LDS, b128 gathers ----------------
__global__ __launch_bounds__(256, 4) void score_v4(const float* __restrict__ pq, const int* __restrict__ ei,
                                                   const float* __restrict__ wm2, const float* __restrict__ bm2,
                                                   float* __restrict__ out) {
  __shared__ float Ps[256 * 20];  // 20 KB
  __shared__ float Qs[256 * 20];  // 20 KB
  const int tid = threadIdx.x;
  const int g = blockIdx.x & 127;
  const int quarter = blockIdx.x >> 7;
  const int gbase = g * NPG_;
  const int ebase = g * EPG_ + quarter * 1024;
  int rl[4], cl[4];
  float acc[4] = {};
#pragma unroll
  for (int j = 0; j < 4; ++j) {
    int e = ebase + j * 256 + tid;
    rl[j] = (ei[e] - gbase) * 20;
    cl[j] = (ei[EE_ + e] - gbase) * 20;
  }
  for (int t = 0; t < 16; ++t) {
    __syncthreads();
#pragma unroll
    for (int it = 0; it < 4; ++it) {
      int idx = tid + it * 256;
      int node = idx >> 2, k4 = (idx & 3) * 4;
      const float* src = &pq[(size_t)(gbase + node) * 512 + t * 16 + k4];
      *(float4*)&Ps[node * 20 + k4] = *(const float4*)src;
      *(float4*)&Qs[node * 20 + k4] = *(const float4*)(src + 256);
    }
    __syncthreads();
#pragma unroll
    for (int k4 = 0; k4 < 16; k4 += 4) {
      float4 w4 = *(const float4*)&wm2[t * 16 + k4];
#pragma unroll
      for (int j = 0; j < 4; ++j) {
        float4 p = *(const float4*)&Ps[rl[j] + k4];
        float4 q = *(const float4*)&Qs[cl[j] + k4];
        acc[j] = fmaf(w4.x, fmaxf(p.x + q.x, 0.f), acc[j]);
        acc[j] = fmaf(w4.y, fmaxf(p.y + q.y, 0.f), acc[j]);
        acc[j] = fmaf(w4.z, fmaxf(p.z + q.z, 0.f), acc[j]);
        acc[j] = fmaf(w4.w, fmaxf(p.w + q.w, 0.f), acc[j]);
      }
    }
  }
  const float beta = bm2[0];
#pragma unroll
  for (int j = 0; j < 4; ++j) out[ebase + j * 256 + tid] = acc[j] + beta;
}

// ---------------- bitonic argsort v4 (proven): registers + shfl_xor; LDS only for j>=256 ----------------
__global__ __launch_bounds__(1024) void sort_kernel(float* __restrict__ out, const int* __restrict__ ei,
                                                    int* __restrict__ kg, int* __restrict__ dg,
                                                    int* __restrict__ cmask, int* __restrict__ dmask) {
  __shared__ u64 keys[EPG_];
  const int g = blockIdx.x;
  const int tid = threadIdx.x;
  const int b = 4 * tid;
  u64 e[4];
  {
    float4 s4 = *(const float4*)&out[g * EPG_ + b];
    float sv[4] = {s4.x, s4.y, s4.z, s4.w};
#pragma unroll
    for (int s = 0; s < 4; ++s) {
      unsigned u = __float_as_uint(sv[s]);
      u = (u & 0x80000000u) ? ~u : (u | 0x80000000u);
      e[s] = ((u64)u << 32) | (unsigned)(~(b + s));
    }
  }
  cswap(e[0], e[1], true);
  cswap(e[2], e[3], false);
  {
    bool d = ((b & 4) == 0);
    cswap(e[0], e[2], d); cswap(e[1], e[3], d);
    cswap(e[0], e[1], d); cswap(e[2], e[3], d);
  }
  for (int k = 8; k <= EPG_; k <<= 1) {
    if (k >= 512) {
#pragma unroll
      for (int s = 0; s < 4; ++s) keys[b + s] = e[s];
      __syncthreads();
      for (int j = k >> 1; j >= 256; j >>= 1) {
        const int jm1 = j - 1;
        const int p0 = tid, p1 = tid + 1024;
        const int i0 = ((p0 & ~jm1) << 1) | (p0 & jm1);
        const int i1 = ((p1 & ~jm1) << 1) | (p1 & jm1);
        u64 a0 = keys[i0], b0 = keys[i0 + j];
        u64 a1 = keys[i1], b1 = keys[i1 + j];
        bool d0 = ((i0 & k) == 0), d1 = ((i1 & k) == 0);
        u64 hi0 = a0 > b0 ? a0 : b0, lo0 = a0 > b0 ? b0 : a0;
        u64 hi1 = a1 > b1 ? a1 : b1, lo1 = a1 > b1 ? b1 : a1;
        keys[i0]     = d0 ? hi0 : lo0;
        keys[i0 + j] = d0 ? lo0 : hi0;
        keys[i1]     = d1 ? hi1 : lo1;
        keys[i1 + j] = d1 ? lo1 : hi1;
        __syncthreads();
      }
#pragma unroll
      for (int s = 0; s < 4; ++s) e[s] = keys[b + s];
    }
    const bool d = ((tid & (k >> 2)) == 0);
    for (int j = (k >> 1) > 128 ? 128 : (k >> 1); j >= 4; j >>= 1) {
      const int delta = j >> 2;
      const bool lower = ((tid & delta) == 0);
      const bool keepmax = (lower == d);
#pragma unroll
      for (int s = 0; s < 4; ++s) {
        u64 p = __shfl_xor(e[s], delta);
        u64 mx = e[s] > p ? e[s] : p;
        u64 mn = e[s] > p ? p : e[s];
        e[s] = keepmax ? mx : mn;
      }
    }
    cswap(e[0], e[2], d); cswap(e[1], e[3], d);
    cswap(e[0], e[1], d); cswap(e[2], e[3], d);
  }
#pragma unroll
  for (int s = 0; s < 4; ++s) {
    const int p = b + s;
    u64 kv = e[s];
    int i = (int)(~(unsigned)kv);
    unsigned hi = (unsigned)(kv >> 32);
    unsigned ub = (hi & 0x80000000u) ? (hi ^ 0x80000000u) : ~hi;
    float sc = __uint_as_float(ub);
    int ed = g * EPG_ + i;
    int r = ei[ed], c = ei[EE_ + ed];
    if (p < KK_) {
      out[O_CW + g * KK_ + p] = sc;
      kg[g * KK_ + p] = ed;
      cmask[r] = 1; cmask[c] = 1;
    } else {
      int q = p - KK_;
      out[O_DW + g * KK_ + q] = -sc;
      dg[g * KK_ + q] = ed;
      dmask[r] = 1; dmask[c] = 1;
    }
  }
}

// ---------------- inclusive scan of masks -> nid (cumsum-1); 1 block per mask ----------------
__global__ __launch_bounds__(1024) void scan_kernel(const int* __restrict__ masks, int* __restrict__ nids) {
  const int which = blockIdx.x;
  const int* m = masks + which * NN_;
  int* nid = nids + which * NN_;
  const int tid = threadIdx.x;
  const int base = tid * 32;
  int local[32];
  int sum = 0;
#pragma unroll
  for (int j = 0; j < 32; ++j) { local[j] = m[base + j]; sum += local[j]; }
  __shared__ int ps[1024];
  ps[tid] = sum;
  __syncthreads();
  for (int off = 1; off < 1024; off <<= 1) {
    int v = (tid >= off) ? ps[tid - off] : 0;
    __syncthreads();
    ps[tid] += v;
    __syncthreads();
  }
  int run = ps[tid] - sum;
#pragma unroll
  for (int j = 0; j < 32; ++j) { run += local[j]; nid[base + j] = run - 1; }
}

// ---------------- final gathers ----------------
__global__ __launch_bounds__(256) void finalize_kernel(const int* __restrict__ kg, const int* __restrict__ dg,
                                                       const int* __restrict__ ei,
                                                       const int* __restrict__ nid_c, const int* __restrict__ nid_d,
                                                       const int* __restrict__ cmask, const int* __restrict__ dmask,
                                                       float* __restrict__ out) {
  const int p = blockIdx.x * 256 + threadIdx.x;
  int e = kg[p];
  out[O_CEI + p]       = (float)nid_c[ei[e]];
  out[O_CEI + GK_ + p] = (float)nid_c[ei[EE_ + e]];
  int e2 = dg[p];
  out[O_FEI + p]       = (float)nid_d[ei[e2]];
  out[O_FEI + GK_ + p] = (float)nid_d[ei[EE_ + e2]];
  if (p < NN_) {
    out[O_CM + p] = (float)cmask[p];
    out[O_DM + p] = (float)dmask[p];
  }
}

extern "C" void kernel_launch(void* const* d_in, const int* in_sizes, int n_in,
                              void* d_out, int out_size, void* d_ws, size_t ws_size,
                              hipStream_t stream) {
  (void)in_sizes; (void)n_in; (void)out_size; (void)ws_size;
  const float* x   = (const float*)d_in[0];
  const float* ea  = (const float*)d_in[1];
  const float* W11 = (const float*)d_in[2];
  const float* b11 = (const float*)d_in[3];
  const float* W12 = (const float*)d_in[4];
  const float* W13 = (const float*)d_in[5];
  const float* b13 = (const float*)d_in[6];
  const float* W21 = (const float*)d_in[7];
  const float* b21 = (const float*)d_in[8];
  const float* W22 = (const float*)d_in[9];
  const float* W23 = (const float*)d_in[10];
  const float* b23 = (const float*)d_in[11];
  const float* Wm1 = (const float*)d_in[12];
  const float* bm1 = (const float*)d_in[13];
  const float* Wm2 = (const float*)d_in[14];
  const float* bm2 = (const float*)d_in[15];
  const int*   ei  = (const int*)d_in[16];
  float* out = (float*)d_out;
  float* ws  = (float*)d_ws;

  // workspace (float offsets), phase-overlapped (unchanged 78.1 MB footprint):
  //   MT  [0, 8388608)          32 MB   (dead after mm_agg #2; fully written by build_dense — no memset)
  //   Wc  [8388608, 8421376)    128 KB  (fully written by build_dense)
  //   buf [8421376, 14712832)   24 MB   (dead after mm_agg #2)
  //   pq  [0, 16777216)         64 MB   overlaps MT/Wc/buf, written after all dead
  //   h_c [16777216, 18874368)  8 MB
  //   ints from 18874368: kg GK, dg GK, cmask N, dmask N, nid_c N, nid_d N
  //   WT aliases kg: WmT 32768 + W1T 12288 + W2T 12288 = 57344 floats < GK.
  float* MT  = ws;
  float* Wc  = ws + 8388608;
  float* buf = ws + 8421376;
  float* pq  = ws;
  float* h_c = ws + 16777216;
  int* kg    = (int*)(ws + 18874368);
  int* dg    = kg + GK_;
  int* cmask = dg + GK_;
  int* dmask = cmask + NN_;
  int* nid_c = dmask + NN_;
  int* nid_d = nid_c + NN_;
  float* WmT = ws + 18874368;            // aliases kg
  float* W1T = WmT + 32768;
  float* W2T = W1T + 12288;

  prep_kernel<<<160, 256, 0, stream>>>(Wm1, W11, W12, W13, W21, W22, W23, WmT, W1T, W2T, cmask);

  build_dense<<<256, 256, 0, stream>>>(ei, ea, MT, Wc);

  BiasCfg bc1{};
  bc1.b[0] = b11; bc1.b[1] = nullptr; bc1.b[2] = b13;
  gemm_wt<<<512, 256, 0, stream>>>(x, 64, W1T, 192, bc1, 3, buf, 192);

  mm_agg<<<512, 256, 0, stream>>>(MT, buf, Wc, h_c, /*relu=*/1);

  BiasCfg bc2{};
  bc2.b[0] = b21; bc2.b[1] = nullptr; bc2.b[2] = b23;
  gemm_wt<<<512, 256, 0, stream>>>(h_c, 64, W2T, 192, bc2, 3, buf, 192);

  mm_agg<<<512, 256, 0, stream>>>(MT, buf, Wc, h_c, /*relu=*/0);

  BiasCfg bc3{};
  for (int cb = 0; cb < 4; ++cb) { bc3.b[cb] = bm1 + cb * 64; bc3.b[cb + 4] = nullptr; }
  gemm_wt<<<512, 256, 0, stream>>>(h_c, 64, WmT, 512, bc3, 8, pq, 512);

  score_v4<<<512, 256, 0, stream>>>(pq, ei, Wm2, bm2, out);

  sort_kernel<<<G_, 1024, 0, stream>>>(out, ei, kg, dg, cmask, dmask);

  scan_kernel<<<2, 1024, 0, stream>>>(cmask, nid_c);

  finalize_kernel<<<GK_ / 256, 256, 0, stream>>>(kg, dg, ei, nid_c, nid_d, cmask, dmask, out);
}

// Round 16
// 328.126 us; speedup vs baseline: 7.2268x; 1.0029x over previous
//
#include <hip/hip_runtime.h>
#include <cstddef>

#define G_    128
#define NPG_  256
#define EPG_  4096
#define NN_   32768
#define EE_   524288
#define KK_   2048
#define GK_   262144

// d_out layout (floats): [score E][causal_w GK][conf_w GK][causal_ei 2*GK][conf_ei 2*GK][cmask N][dmask N]
#define O_CW  524288
#define O_DW  786432
#define O_CEI 1048576
#define O_FEI 1572864
#define O_CM  2097152
#define O_DM  2129920

typedef float v4f __attribute__((ext_vector_type(4)));
typedef unsigned long long u64;

struct BiasCfg {
  const float* b[8];
};

__device__ __forceinline__ void cswap(u64& a, u64& b, bool d) {
  u64 hi = a > b ? a : b, lo = a > b ? b : a;
  a = d ? hi : lo;
  b = d ? lo : hi;
}

// ---------------- GEMM body, W from pre-transposed global; nt-envelope rule (r6/7/8/9/13):
// <=1 outstanding nt panel stream per block — enforce with __syncthreads() AFTER each cb's
// store burst. Removing that barrier (r13) caused ~20x HBM write amplification. ----------------
__device__ __forceinline__ void gemm_wt_body(const float* __restrict__ in, int istride,
                                             const float* __restrict__ WT, int wstride,
                                             const BiasCfg& bc, int ncb,
                                             float* __restrict__ out, int ostride,
                                             int bx, float* xT) {
  const int tid = threadIdx.x;
  const int r0 = bx * 64;
#pragma unroll
  for (int it = 0; it < 16; ++it) {
    int idx = tid + it * 256;
    int rr = idx >> 6, kk = idx & 63;
    xT[kk * 68 + rr] = in[(r0 + rr) * istride + kk];
  }
  __syncthreads();
  const int c4 = (tid & 15) * 4;
  const int r4 = (tid >> 4) * 4;
  for (int cb = 0; cb < ncb; ++cb) {
    const float* wp = WT + cb * 64 + c4;
    const float* bp = bc.b[cb];
    float acc[4][4] = {};
#pragma unroll
    for (int k = 0; k < 64; ++k) {
      float4 xv = *(const float4*)&xT[k * 68 + r4];
      float4 wv = *(const float4*)&wp[(size_t)k * wstride];
      float xr[4] = {xv.x, xv.y, xv.z, xv.w};
      float wc[4] = {wv.x, wv.y, wv.z, wv.w};
#pragma unroll
      for (int a = 0; a < 4; ++a)
#pragma unroll
        for (int b = 0; b < 4; ++b)
          acc[a][b] = fmaf(xr[a], wc[b], acc[a][b]);
    }
    float bx4[4] = {0.f, 0.f, 0.f, 0.f};
    if (bp) {
      float4 bb = *(const float4*)&bp[c4];
      bx4[0] = bb.x; bx4[1] = bb.y; bx4[2] = bb.z; bx4[3] = bb.w;
    }
#pragma unroll
    for (int ri = 0; ri < 4; ++ri) {
      v4f st;
      st.x = acc[ri][0] + bx4[0];
      st.y = acc[ri][1] + bx4[1];
      st.z = acc[ri][2] + bx4[2];
      st.w = acc[ri][3] + bx4[3];
      __builtin_nontemporal_store(st, (v4f*)&out[(r0 + r4 + ri) * ostride + cb * 64 + c4]);
    }
    __syncthreads();  // drain nt burst (vmcnt(0)) — the nt-envelope invariant
  }
}

__global__ __launch_bounds__(256, 4) void gemm_wt(const float* __restrict__ in, int istride,
                                                  const float* __restrict__ WT, int wstride,
                                                  BiasCfg bc, int ncb,
                                                  float* __restrict__ out, int ostride) {
  __shared__ float xT[64 * 68];
  gemm_wt_body(in, istride, WT, wstride, bc, ncb, out, ostride, blockIdx.x, xT);
}

// ---------------- prep: weight transposes (WmT/W1T/W2T) + zero masks ----------------
__global__ __launch_bounds__(256) void prep_kernel(const float* __restrict__ Wm1,
                                                   const float* __restrict__ W11, const float* __restrict__ W12,
                                                   const float* __restrict__ W13,
                                                   const float* __restrict__ W21, const float* __restrict__ W22,
                                                   const float* __restrict__ W23,
                                                   float* __restrict__ WmT, float* __restrict__ W1T,
                                                   float* __restrict__ W2T, int* __restrict__ masks) {
  const int b = blockIdx.x;
  const int tid = threadIdx.x;
  if (b < 64) {
    const int k = b;
#pragma unroll
    for (int t = 0; t < 2; ++t) {
      int j = t * 256 + tid;
      int row = j & 255;
      int koff = (j < 256) ? 0 : 64;
      WmT[k * 512 + j] = Wm1[row * 128 + koff + k];
    }
  } else if (b < 80) {
    const int kb = (b - 64) * 4;
    if (tid < 192) {
      int cb = tid >> 6, c = tid & 63;
      const float* Wsrc = (cb == 0) ? W11 : (cb == 1) ? W12 : W13;
#pragma unroll
      for (int s = 0; s < 4; ++s) {
        int k = kb + s;
        W1T[k * 192 + tid] = Wsrc[c * 64 + k];
      }
    }
  } else if (b < 96) {
    const int kb = (b - 80) * 4;
    if (tid < 192) {
      int cb = tid >> 6, c = tid & 63;
      const float* Wsrc = (cb == 0) ? W21 : (cb == 1) ? W22 : W23;
#pragma unroll
      for (int s = 0; s < 4; ++s) {
        int k = kb + s;
        W2T[k * 192 + tid] = Wsrc[c * 64 + k];
      }
    }
  } else {
    int idx = (b - 96) * 1024 + tid * 4;  // 64 blocks x 1024 ints = 65536 = 2*NN
    int4 z = {0, 0, 0, 0};
    *(int4*)&masks[idx] = z;
  }
}

// ---------------- build_dense: per-(group, col-half) LDS accumulation — no global atomics,
// no MT memset (every cell written), Wc = LDS column sums (no contention) ----------------
__global__ __launch_bounds__(256) void build_dense(const int* __restrict__ ei, const float* __restrict__ ea,
                                                   float* __restrict__ MT, float* __restrict__ Wc) {
  __shared__ float acc[NPG_ * 128];  // 128 KB: 256 rows x 128 cols (this block's column half)
  const int tid = threadIdx.x;
  const int g = blockIdx.x >> 1;
  const int c0 = (blockIdx.x & 1) * 128;
  const int gbase = g * NPG_;
  const size_t mbase = (size_t)g << 16;
  for (int i = tid * 4; i < NPG_ * 128; i += 1024) {
    float4 z = {0.f, 0.f, 0.f, 0.f};
    *(float4*)&acc[i] = z;
  }
  __syncthreads();
  const int ebase = g * EPG_;
#pragma unroll
  for (int it = 0; it < 16; ++it) {
    int e = ebase + it * 256 + tid;
    int r = ei[e] - gbase;
    int ch = ei[EE_ + e] - gbase - c0;
    float w = ea[e];
    if ((unsigned)ch < 128u) atomicAdd(&acc[r * 128 + ch], w);
  }
  __syncthreads();
  // write the half-slab: each row contributes 512 B aligned chunk
  for (int i = tid; i < NPG_ * 32; i += 256) {
    int r = i >> 5, c4 = (i & 31) * 4;
    *(float4*)&MT[mbase + (size_t)r * 256 + c0 + c4] = *(const float4*)&acc[r * 128 + c4];
  }
  // Wc column sums (lanes own columns; per-lane serial over r)
  if (tid < 128) {
    float s = 0.f;
    for (int r = 0; r < NPG_; ++r) s += acc[r * 128 + tid];
    Wc[gbase + c0 + tid] = s;
  }
}

// ---------------- dense leconv aggregation: h[c] = sum_r MT[r][c]*A[r] - Wc[c]*B[c] + C[c]
// (v2: float4 staging — 4x fewer global-load and LDS-write instructions) ----------------
__global__ __launch_bounds__(256) void mm_agg(const float* __restrict__ MT, const float* __restrict__ buf,
                                              const float* __restrict__ Wc, float* __restrict__ hout,
                                              int do_relu) {
  __shared__ float Ms[64 * 72];
  __shared__ float As[64 * 72];
  const int tid = threadIdx.x;
  const int g = blockIdx.x >> 2;
  const int c0 = (blockIdx.x & 3) * 64;
  const int gbase = g * NPG_;
  const size_t mbase = (size_t)g << 16;
  const int c4 = (tid >> 4) * 4;   // output node within tile
  const int k4 = (tid & 15) * 4;   // feature (lane-contiguous)
  float acc[4][4] = {};
  for (int kc = 0; kc < 4; ++kc) {
#pragma unroll
    for (int it = 0; it < 4; ++it) {
      int idx = tid + it * 256;       // 0..1023
      int rr = idx >> 4, c16 = (idx & 15) * 4;
      *(float4*)&Ms[rr * 72 + c16] = *(const float4*)&MT[mbase + (size_t)(kc * 64 + rr) * 256 + c0 + c16];
      *(float4*)&As[rr * 72 + c16] = *(const float4*)&buf[(gbase + kc * 64 + rr) * 192 + c16];
    }
    __syncthreads();
#pragma unroll
    for (int r = 0; r < 64; ++r) {
      float4 mv = *(const float4*)&Ms[r * 72 + c4];
      float4 av = *(const float4*)&As[r * 72 + k4];
      float mr[4] = {mv.x, mv.y, mv.z, mv.w};
      float ak[4] = {av.x, av.y, av.z, av.w};
#pragma unroll
      for (int ci = 0; ci < 4; ++ci)
#pragma unroll
        for (int ki = 0; ki < 4; ++ki)
          acc[ci][ki] = fmaf(mr[ci], ak[ki], acc[ci][ki]);
    }
    __syncthreads();
  }
#pragma unroll
  for (int ci = 0; ci < 4; ++ci) {
    int n = gbase + c0 + c4 + ci;
    float wcn = Wc[n];
    float4 b4 = *(const float4*)&buf[n * 192 + 64 + k4];
    float4 cc4 = *(const float4*)&buf[n * 192 + 128 + k4];
    float4 st;
    st.x = acc[ci][0] - wcn * b4.x + cc4.x;
    st.y = acc[ci][1] - wcn * b4.y + cc4.y;
    st.z = acc[ci][2] - wcn * b4.z + cc4.z;
    st.w = acc[ci][3] - wcn * b4.w + cc4.w;
    if (do_relu) {
      st.x = fmaxf(st.x, 0.f); st.y = fmaxf(st.y, 0.f);
      st.z = fmaxf(st.z, 0.f); st.w = fmaxf(st.w, 0.f);
    }
    *(float4*)&hout[n * 64 + k4] = st;
  }
}

// ---------------- fused edge scores v5: 1024 blocks (512 edges each) -> 4 blocks/CU,
// double latency-hiding for the statistical bank-quad conflicts of the random gather ----------------
__global__ __launch_bounds__(256, 4) void score_v5(const float* __restrict__ pq, const int* __restrict__ ei,
                                                   const float* __restrict__ wm2, const float* __restrict__ bm2,
                                                   float* __restrict__ out) {
  __shared__ float Ps[256 * 20];  // 20 KB
  __shared__ float Qs[256 * 20];  // 20 KB  (40 KB -> exactly 4 blocks/CU)
  const int tid = threadIdx.x;
  const int g = blockIdx.x & 127;       // same-g blocks all ≡ g (mod 8) -> same XCD, pq L2 reuse
  const int eighth = blockIdx.x >> 7;
  const int gbase = g * NPG_;
  const int ebase = g * EPG_ + eighth * 512;
  int rl[2], cl[2];
  float acc[2] = {};
#pragma unroll
  for (int j = 0; j < 2; ++j) {
    int e = ebase + j * 256 + tid;
    rl[j] = (ei[e] - gbase) * 20;
    cl[j] = (ei[EE_ + e] - gbase) * 20;
  }
  for (int t = 0; t < 16; ++t) {
    __syncthreads();
#pragma unroll
    for (int it = 0; it < 4; ++it) {
      int idx = tid + it * 256;
      int node = idx >> 2, k4 = (idx & 3) * 4;
      const float* src = &pq[(size_t)(gbase + node) * 512 + t * 16 + k4];
      *(float4*)&Ps[node * 20 + k4] = *(const float4*)src;
      *(float4*)&Qs[node * 20 + k4] = *(const float4*)(src + 256);
    }
    __syncthreads();
#pragma unroll
    for (int k4 = 0; k4 < 16; k4 += 4) {
      float4 w4 = *(const float4*)&wm2[t * 16 + k4];
#pragma unroll
      for (int j = 0; j < 2; ++j) {
        float4 p = *(const float4*)&Ps[rl[j] + k4];
        float4 q = *(const float4*)&Qs[cl[j] + k4];
        acc[j] = fmaf(w4.x, fmaxf(p.x + q.x, 0.f), acc[j]);
        acc[j] = fmaf(w4.y, fmaxf(p.y + q.y, 0.f), acc[j]);
        acc[j] = fmaf(w4.z, fmaxf(p.z + q.z, 0.f), acc[j]);
        acc[j] = fmaf(w4.w, fmaxf(p.w + q.w, 0.f), acc[j]);
      }
    }
  }
  const float beta = bm2[0];
#pragma unroll
  for (int j = 0; j < 2; ++j) out[ebase + j * 256 + tid] = acc[j] + beta;
}

// ---------------- bitonic argsort v4 (proven): registers + shfl_xor; LDS only for j>=256 ----------------
__global__ __launch_bounds__(1024) void sort_kernel(float* __restrict__ out, const int* __restrict__ ei,
                                                    int* __restrict__ kg, int* __restrict__ dg,
                                                    int* __restrict__ cmask, int* __restrict__ dmask) {
  __shared__ u64 keys[EPG_];
  const int g = blockIdx.x;
  const int tid = threadIdx.x;
  const int b = 4 * tid;
  u64 e[4];
  {
    float4 s4 = *(const float4*)&out[g * EPG_ + b];
    float sv[4] = {s4.x, s4.y, s4.z, s4.w};
#pragma unroll
    for (int s = 0; s < 4; ++s) {
      unsigned u = __float_as_uint(sv[s]);
      u = (u & 0x80000000u) ? ~u : (u | 0x80000000u);
      e[s] = ((u64)u << 32) | (unsigned)(~(b + s));
    }
  }
  cswap(e[0], e[1], true);
  cswap(e[2], e[3], false);
  {
    bool d = ((b & 4) == 0);
    cswap(e[0], e[2], d); cswap(e[1], e[3], d);
    cswap(e[0], e[1], d); cswap(e[2], e[3], d);
  }
  for (int k = 8; k <= EPG_; k <<= 1) {
    if (k >= 512) {
#pragma unroll
      for (int s = 0; s < 4; ++s) keys[b + s] = e[s];
      __syncthreads();
      for (int j = k >> 1; j >= 256; j >>= 1) {
        const int jm1 = j - 1;
        const int p0 = tid, p1 = tid + 1024;
        const int i0 = ((p0 & ~jm1) << 1) | (p0 & jm1);
        const int i1 = ((p1 & ~jm1) << 1) | (p1 & jm1);
        u64 a0 = keys[i0], b0 = keys[i0 + j];
        u64 a1 = keys[i1], b1 = keys[i1 + j];
        bool d0 = ((i0 & k) == 0), d1 = ((i1 & k) == 0);
        u64 hi0 = a0 > b0 ? a0 : b0, lo0 = a0 > b0 ? b0 : a0;
        u64 hi1 = a1 > b1 ? a1 : b1, lo1 = a1 > b1 ? b1 : a1;
        keys[i0]     = d0 ? hi0 : lo0;
        keys[i0 + j] = d0 ? lo0 : hi0;
        keys[i1]     = d1 ? hi1 : lo1;
        keys[i1 + j] = d1 ? lo1 : hi1;
        __syncthreads();
      }
#pragma unroll
      for (int s = 0; s < 4; ++s) e[s] = keys[b + s];
    }
    const bool d = ((tid & (k >> 2)) == 0);
    for (int j = (k >> 1) > 128 ? 128 : (k >> 1); j >= 4; j >>= 1) {
      const int delta = j >> 2;
      const bool lower = ((tid & delta) == 0);
      const bool keepmax = (lower == d);
#pragma unroll
      for (int s = 0; s < 4; ++s) {
        u64 p = __shfl_xor(e[s], delta);
        u64 mx = e[s] > p ? e[s] : p;
        u64 mn = e[s] > p ? p : e[s];
        e[s] = keepmax ? mx : mn;
      }
    }
    cswap(e[0], e[2], d); cswap(e[1], e[3], d);
    cswap(e[0], e[1], d); cswap(e[2], e[3], d);
  }
#pragma unroll
  for (int s = 0; s < 4; ++s) {
    const int p = b + s;
    u64 kv = e[s];
    int i = (int)(~(unsigned)kv);
    unsigned hi = (unsigned)(kv >> 32);
    unsigned ub = (hi & 0x80000000u) ? (hi ^ 0x80000000u) : ~hi;
    float sc = __uint_as_float(ub);
    int ed = g * EPG_ + i;
    int r = ei[ed], c = ei[EE_ + ed];
    if (p < KK_) {
      out[O_CW + g * KK_ + p] = sc;
      kg[g * KK_ + p] = ed;
      cmask[r] = 1; cmask[c] = 1;
    } else {
      int q = p - KK_;
      out[O_DW + g * KK_ + q] = -sc;
      dg[g * KK_ + q] = ed;
      dmask[r] = 1; dmask[c] = 1;
    }
  }
}

// ---------------- inclusive scan of masks -> nid (cumsum-1); 1 block per mask ----------------
__global__ __launch_bounds__(1024) void scan_kernel(const int* __restrict__ masks, int* __restrict__ nids) {
  const int which = blockIdx.x;
  const int* m = masks + which * NN_;
  int* nid = nids + which * NN_;
  const int tid = threadIdx.x;
  const int base = tid * 32;
  int local[32];
  int sum = 0;
#pragma unroll
  for (int j = 0; j < 32; ++j) { local[j] = m[base + j]; sum += local[j]; }
  __shared__ int ps[1024];
  ps[tid] = sum;
  __syncthreads();
  for (int off = 1; off < 1024; off <<= 1) {
    int v = (tid >= off) ? ps[tid - off] : 0;
    __syncthreads();
    ps[tid] += v;
    __syncthreads();
  }
  int run = ps[tid] - sum;
#pragma unroll
  for (int j = 0; j < 32; ++j) { run += local[j]; nid[base + j] = run - 1; }
}

// ---------------- final gathers ----------------
__global__ __launch_bounds__(256) void finalize_kernel(const int* __restrict__ kg, const int* __restrict__ dg,
                                                       const int* __restrict__ ei,
                                                       const int* __restrict__ nid_c, const int* __restrict__ nid_d,
                                                       const int* __restrict__ cmask, const int* __restrict__ dmask,
                                                       float* __restrict__ out) {
  const int p = blockIdx.x * 256 + threadIdx.x;
  int e = kg[p];
  out[O_CEI + p]       = (float)nid_c[ei[e]];
  out[O_CEI + GK_ + p] = (float)nid_c[ei[EE_ + e]];
  int e2 = dg[p];
  out[O_FEI + p]       = (float)nid_d[ei[e2]];
  out[O_FEI + GK_ + p] = (float)nid_d[ei[EE_ + e2]];
  if (p < NN_) {
    out[O_CM + p] = (float)cmask[p];
    out[O_DM + p] = (float)dmask[p];
  }
}

extern "C" void kernel_launch(void* const* d_in, const int* in_sizes, int n_in,
                              void* d_out, int out_size, void* d_ws, size_t ws_size,
                              hipStream_t stream) {
  (void)in_sizes; (void)n_in; (void)out_size; (void)ws_size;
  const float* x   = (const float*)d_in[0];
  const float* ea  = (const float*)d_in[1];
  const float* W11 = (const float*)d_in[2];
  const float* b11 = (const float*)d_in[3];
  const float* W12 = (const float*)d_in[4];
  const float* W13 = (const float*)d_in[5];
  const float* b13 = (const float*)d_in[6];
  const float* W21 = (const float*)d_in[7];
  const float* b21 = (const float*)d_in[8];
  const float* W22 = (const float*)d_in[9];
  const float* W23 = (const float*)d_in[10];
  const float* b23 = (const float*)d_in[11];
  const float* Wm1 = (const float*)d_in[12];
  const float* bm1 = (const float*)d_in[13];
  const float* Wm2 = (const float*)d_in[14];
  const float* bm2 = (const float*)d_in[15];
  const int*   ei  = (const int*)d_in[16];
  float* out = (float*)d_out;
  float* ws  = (float*)d_ws;

  // workspace (float offsets), phase-overlapped (unchanged 78.1 MB footprint):
  //   MT  [0, 8388608)          32 MB   (dead after mm_agg #2; fully written by build_dense — no memset)
  //   Wc  [8388608, 8421376)    128 KB  (fully written by build_dense)
  //   buf [8421376, 14712832)   24 MB   (dead after mm_agg #2)
  //   pq  [0, 16777216)         64 MB   overlaps MT/Wc/buf, written after all dead
  //   h_c [16777216, 18874368)  8 MB
  //   ints from 18874368: kg GK, dg GK, cmask N, dmask N, nid_c N, nid_d N
  //   WT aliases kg: WmT 32768 + W1T 12288 + W2T 12288 = 57344 floats < GK.
  float* MT  = ws;
  float* Wc  = ws + 8388608;
  float* buf = ws + 8421376;
  float* pq  = ws;
  float* h_c = ws + 16777216;
  int* kg    = (int*)(ws + 18874368);
  int* dg    = kg + GK_;
  int* cmask = dg + GK_;
  int* dmask = cmask + NN_;
  int* nid_c = dmask + NN_;
  int* nid_d = nid_c + NN_;
  float* WmT = ws + 18874368;            // aliases kg
  float* W1T = WmT + 32768;
  float* W2T = W1T + 12288;

  prep_kernel<<<160, 256, 0, stream>>>(Wm1, W11, W12, W13, W21, W22, W23, WmT, W1T, W2T, cmask);

  build_dense<<<256, 256, 0, stream>>>(ei, ea, MT, Wc);

  BiasCfg bc1{};
  bc1.b[0] = b11; bc1.b[1] = nullptr; bc1.b[2] = b13;
  gemm_wt<<<512, 256, 0, stream>>>(x, 64, W1T, 192, bc1, 3, buf, 192);

  mm_agg<<<512, 256, 0, stream>>>(MT, buf, Wc, h_c, /*relu=*/1);

  BiasCfg bc2{};
  bc2.b[0] = b21; bc2.b[1] = nullptr; bc2.b[2] = b23;
  gemm_wt<<<512, 256, 0, stream>>>(h_c, 64, W2T, 192, bc2, 3, buf, 192);

  mm_agg<<<512, 256, 0, stream>>>(MT, buf, Wc, h_c, /*relu=*/0);

  BiasCfg bc3{};
  for (int cb = 0; cb < 4; ++cb) { bc3.b[cb] = bm1 + cb * 64; bc3.b[cb + 4] = nullptr; }
  gemm_wt<<<512, 256, 0, stream>>>(h_c, 64, WmT, 512, bc3, 8, pq, 512);

  score_v5<<<1024, 256, 0, stream>>>(pq, ei, Wm2, bm2, out);

  sort_kernel<<<G_, 1024, 0, stream>>>(out, ei, kg, dg, cmask, dmask);

  scan_kernel<<<2, 1024, 0, stream>>>(cmask, nid_c);

  finalize_kernel<<<GK_ / 256, 256, 0, stream>>>(kg, dg, ei, nid_c, nid_d, cmask, dmask, out);
}